// Round 1
// baseline (85.021 us; speedup 1.0000x reference)
//
#include <hip/hip_runtime.h>

// Problem constants (match reference)
#define BATCH      8192
#define D_DIM      512
#define NUM_CLS    90
#define K_CENTERS  8

// One wave (64 lanes) per sample.
// Lane layout: k = lane & 7 (which center), sub = lane >> 3 (which 64-elem chunk of D).
// Each lane: 64-elem fp32 dot via 16 float4 FMA iterations.
// Reduce over sub with shfl_xor(8,16,32); then over k with shfl_xor(1,2,4) on (d, d*d).
__global__ __launch_bounds__(256) void center_loss_main(
    const float* __restrict__ x,
    const float* __restrict__ centers,
    const int*   __restrict__ labels,
    double*      __restrict__ partials)
{
    const int wave = threadIdx.x >> 6;   // 0..3
    const int lane = threadIdx.x & 63;
    const int k    = lane & 7;
    const int sub  = lane >> 3;

    const int b = blockIdx.x * 4 + wave;

    __shared__ double s_r[4];

    double r = 0.0;
    if (b < BATCH) {
        const int label = labels[b];
        // float4 index: sub + 8*i  -> float offset sub*4 + 32*i (contiguous 128B per iter across sub)
        const float4* xr = (const float4*)(x + (size_t)b * D_DIM) + sub;
        const float4* cr = (const float4*)(centers + ((size_t)label * K_CENTERS + k) * D_DIM) + sub;

        float acc = 0.0f;
#pragma unroll
        for (int i = 0; i < 16; ++i) {
            float4 xv = xr[i * 8];
            float4 cv = cr[i * 8];
            acc = fmaf(xv.x, cv.x, acc);
            acc = fmaf(xv.y, cv.y, acc);
            acc = fmaf(xv.z, cv.z, acc);
            acc = fmaf(xv.w, cv.w, acc);
        }
        // reduce across sub (lane bits 3..5)
        acc += __shfl_xor(acc, 8);
        acc += __shfl_xor(acc, 16);
        acc += __shfl_xor(acc, 32);

        const float dk = 1.0f + acc;     // d[b,k], replicated across sub-groups
        float s1 = dk;
        float s2 = dk * dk;
        // reduce across k (lane bits 0..2)
        s1 += __shfl_xor(s1, 1);  s2 += __shfl_xor(s2, 1);
        s1 += __shfl_xor(s1, 2);  s2 += __shfl_xor(s2, 2);
        s1 += __shfl_xor(s1, 4);  s2 += __shfl_xor(s2, 4);

        r = (double)(s2 / s1);           // sum_k w*d = (sum d^2) / (sum d)
    }

    if (lane == 0) s_r[wave] = r;
    __syncthreads();
    if (threadIdx.x == 0) {
        partials[blockIdx.x] = s_r[0] + s_r[1] + s_r[2] + s_r[3];
    }
}

// Single-block reduction of per-block double partials -> float mean.
__global__ __launch_bounds__(256) void center_loss_reduce(
    const double* __restrict__ partials,
    float*        __restrict__ out,
    int n)
{
    double s = 0.0;
    for (int i = threadIdx.x; i < n; i += 256) s += partials[i];

    s += __shfl_xor(s, 1);
    s += __shfl_xor(s, 2);
    s += __shfl_xor(s, 4);
    s += __shfl_xor(s, 8);
    s += __shfl_xor(s, 16);
    s += __shfl_xor(s, 32);

    __shared__ double sm[4];
    const int wave = threadIdx.x >> 6;
    const int lane = threadIdx.x & 63;
    if (lane == 0) sm[wave] = s;
    __syncthreads();
    if (threadIdx.x == 0) {
        double t = sm[0] + sm[1] + sm[2] + sm[3];
        out[0] = (float)(t / (double)BATCH);
    }
}

extern "C" void kernel_launch(void* const* d_in, const int* in_sizes, int n_in,
                              void* d_out, int out_size, void* d_ws, size_t ws_size,
                              hipStream_t stream) {
    const float* x       = (const float*)d_in[0];
    const float* centers = (const float*)d_in[1];
    const int*   labels  = (const int*)d_in[2];
    float*  out      = (float*)d_out;
    double* partials = (double*)d_ws;   // 2048 doubles = 16 KB

    const int nblocks = BATCH / 4;      // 4 samples (waves) per block
    center_loss_main<<<nblocks, 256, 0, stream>>>(x, centers, labels, partials);
    center_loss_reduce<<<1, 256, 0, stream>>>(partials, out, nblocks);
}